// Round 1
// 326.049 us; speedup vs baseline: 1.0763x; 1.0763x over previous
//
#include <hip/hip_runtime.h>
#include <cstdint>
#include <cstddef>

// Instant-NGP hash-grid encode, R6.
//
// History: R1 fused = 247 us kernel (748 MB L2 thrash from hashed tables).
// R4 two-phase = 210 us kernels; R5 hashed-only phase 1 + dense-recompute
// phase 2 = 350.7 us harness (~130 us/kernel, rest fixed overhead).
// R5 counters: gather_out 130 us, VALUBusy 7.8%, HBM 17% -> address-path
// (TA/L1 line-transaction) bound, NOT bandwidth bound.
//
// R6 changes:
//  - gather_out: out[p][32] row stores were 64-line scatters per instr
//    (each lane's 16 B in its own line, stride 128 B) = 512 line-touches
//    per wave just for stores. Now: XOR-swizzled LDS transpose (16 KB,
//    two 128-point flushes, b128-aligned, bank-conflict-free) then fully
//    coalesced full-line nontemporal stores (16 lines/instr, no L2
//    partial-line merging). Full-line nt is safe; R3's write blow-up was
//    nt on partial lines.
//  - hashed_level_kernel: hash = (x ^ y*P1 ^ z*P2) & (T-1); x enters by
//    XOR, so for even cx the two x-corners are entries {idx0, idx0^1} =
//    an adjacent 16 B-aligned pair -> one dwordx4 gather instead of two
//    dwordx2. ~Half the lanes take this path: expected -25% divergent
//    addresses. Select order by idx0&1 (branchless within the path).

namespace {

constexpr int      kNLevels = 16;
constexpr uint32_t kT       = 1u << 19;             // 524288 entries / level
constexpr uint32_t kP1      = 2654435761u;           // tcnn hash primes (y, z)
constexpr uint32_t kP2      = 805459861u;

typedef float v2f __attribute__((ext_vector_type(2)));
typedef float v4f __attribute__((ext_vector_type(4)));

// floor(16 * scale^lv) + 1, scale = exp((ln 2048 - ln 16)/15)
__device__ constexpr int kRes[kNLevels] = {
    17, 23, 31, 43, 59, 81, 112, 154, 213, 295, 407, 562, 777, 1073, 1483, 2049
};
// dense iff res^3 <= T  <=>  res <= 80; levels 0..4 dense, 5..15 hashed.

__device__ inline void corner_setup(float px, float py, float pz, int res,
                                    int& cx, int& cy, int& cz,
                                    float& wx, float& wy, float& wz) {
    const float s = (float)(res - 1);
    const float fx = px * s, fy = py * s, fz = pz * s;
    cx = (int)floorf(fx); cy = (int)floorf(fy); cz = (int)floorf(fz);
    cx = min(max(cx, 0), res - 2);
    cy = min(max(cy, 0), res - 2);
    cz = min(max(cz, 0), res - 2);
    wx = fx - (float)cx; wy = fy - (float)cy; wz = fz - (float)cz;
}

// ---------- Phase 1: hashed levels 5..15, one blockIdx.y slice per level ----
__global__ __launch_bounds__(256) void hashed_level_kernel(
    const float* __restrict__ x, const float* __restrict__ table,
    const float* __restrict__ mask, float* __restrict__ ws, int n)
{
    const int lv = 5 + blockIdx.y;
    const float m0 = mask[2 * lv], m1 = mask[2 * lv + 1];
    if (m0 == 0.0f && m1 == 0.0f) return;   // masked level: slice exits

    const int p = blockIdx.x * blockDim.x + threadIdx.x;
    if (p >= n) return;
    const float px = x[3 * p + 0];
    const float py = x[3 * p + 1];
    const float pz = x[3 * p + 2];

    const int res = kRes[lv];
    int cx, cy, cz; float wx, wy, wz;
    corner_setup(px, py, pz, res, cx, cy, cz, wx, wy, wz);
    const float ux = 1.0f - wx, uy = 1.0f - wy, uz = 1.0f - wz;
    const float* __restrict__ tbl = table + (size_t)lv * (size_t)(kT * 2);

    // hash components (CSE'd): idx = (cx+dx) ^ hy[dy] ^ hz[dz], masked
    const uint32_t hy0 = (uint32_t)cy * kP1, hy1 = (uint32_t)(cy + 1) * kP1;
    const uint32_t hz0 = (uint32_t)cz * kP2, hz1 = (uint32_t)(cz + 1) * kP2;
    const uint32_t cxu = (uint32_t)cx;

    float r0 = 0.0f, r1 = 0.0f;
    if ((cx & 1) == 0) {
        // even cx: x-corner pair is {idx0, idx0^1} -> one aligned 16 B gather
#pragma unroll
        for (int c = 0; c < 4; ++c) {
            const uint32_t h = ((c & 1) ? hy1 : hy0) ^ ((c >> 1) ? hz1 : hz0);
            const uint32_t i0 = (cxu ^ h) & (kT - 1u);
            const v4f ab = *(const v4f*)(tbl + 2u * (i0 & ~1u));
            const float wyz = ((c & 1) ? wy : uy) * ((c >> 1) ? wz : uz);
            const float w0 = ux * wyz, w1 = wx * wyz;
            const bool sw = (i0 & 1u) != 0u;   // odd idx0: corner0 in .zw
            r0 = fmaf(sw ? ab.z : ab.x, w0, fmaf(sw ? ab.x : ab.z, w1, r0));
            r1 = fmaf(sw ? ab.w : ab.y, w0, fmaf(sw ? ab.y : ab.w, w1, r1));
        }
    } else {
#pragma unroll
        for (int c = 0; c < 8; ++c) {
            const int dx = c & 1, dy = (c >> 1) & 1, dz = (c >> 2) & 1;
            const uint32_t idx =
                ((cxu + (uint32_t)dx) ^ (dy ? hy1 : hy0) ^ (dz ? hz1 : hz0))
                & (kT - 1u);
            const v2f v = *(const v2f*)(tbl + 2u * idx);
            const float w = (dx ? wx : ux) * (dy ? wy : uy) * (dz ? wz : uz);
            r0 = fmaf(v.x, w, r0);
            r1 = fmaf(v.y, w, r1);
        }
    }
    v2f o; o.x = r0; o.y = r1;
    // full-line coalesced (64 lanes x 8 B contiguous): nt is safe here
    __builtin_nontemporal_store(
        o, (v2f*)(ws + ((size_t)(lv - 5) * n + p) * 2));
}

// ---------- Phase 2: dense recompute + hashed readback -> out[N][32] --------
// Output now staged through LDS so global stores are full-line coalesced.
// Swizzled layout: row r (point within half), chunk c (16 B) lives at
// float offset r*32 + ((c ^ (r&7)) << 2) -> b128-aligned, conflict-free
// on both the per-row writes and the linear copy reads.
__global__ __launch_bounds__(256) void gather_out_kernel(
    const float* __restrict__ x, const float* __restrict__ table,
    const float* __restrict__ ws, const float* __restrict__ mask,
    float* __restrict__ out, int n)
{
    __shared__ float lds[128 * 32];             // 16 KB: one 128-point half

    const int tid = threadIdx.x;
    const int p   = blockIdx.x * 256 + tid;
    const int pc  = (p < n) ? p : (n - 1);      // clamp: no early return (barriers)

    const float px = x[3 * pc + 0];
    const float py = x[3 * pc + 1];
    const float pz = x[3 * pc + 2];

    v4f o[8];

    // dense levels 0..4: recompute (tables 2.65 MB, chip-wide L2-hot).
#pragma unroll
    for (int lv = 0; lv < 5; ++lv) {
        const float m0 = mask[2 * lv], m1 = mask[2 * lv + 1];
        float r0 = 0.0f, r1 = 0.0f;
        if (m0 != 0.0f || m1 != 0.0f) {
            const int res = kRes[lv];
            int cx, cy, cz; float wx, wy, wz;
            corner_setup(px, py, pz, res, cx, cy, cz, wx, wy, wz);
            const float ux = 1.0f - wx, uy = 1.0f - wy, uz = 1.0f - wz;
            const float* __restrict__ tbl = table + (size_t)lv * (size_t)(kT * 2);
#pragma unroll
            for (int c = 0; c < 4; ++c) {
                const int dy = c & 1, dz = (c >> 1) & 1;
                const uint32_t idx0 =
                    (uint32_t)(cx + res * ((cy + dy) + res * (cz + dz)));
                // entries idx0 and idx0+1 are the two x-corners: one 16 B load
                v4f ab;
                __builtin_memcpy(&ab, tbl + 2u * idx0, sizeof(v4f));
                const float wyz = (dy ? wy : uy) * (dz ? wz : uz);
                const float w0 = ux * wyz, w1 = wx * wyz;
                r0 = fmaf(ab.x, w0, fmaf(ab.z, w1, r0));
                r1 = fmaf(ab.y, w0, fmaf(ab.w, w1, r1));
            }
            r0 *= m0; r1 *= m1;
        }
        if (lv & 1) { o[lv >> 1].z = r0; o[lv >> 1].w = r1; }
        else        { o[lv >> 1].x = r0; o[lv >> 1].y = r1; }
    }

    // hashed levels 5..15: read phase-1 results from ws.
#pragma unroll
    for (int lv = 5; lv < kNLevels; ++lv) {
        const float m0 = mask[2 * lv], m1 = mask[2 * lv + 1];
        float r0 = 0.0f, r1 = 0.0f;
        if (m0 != 0.0f || m1 != 0.0f) {
            const v2f v = __builtin_nontemporal_load(
                (const v2f*)(ws + ((size_t)(lv - 5) * n + pc) * 2));
            r0 = v.x * m0;
            r1 = v.y * m1;
        }
        if (lv & 1) { o[lv >> 1].z = r0; o[lv >> 1].w = r1; }
        else        { o[lv >> 1].x = r0; o[lv >> 1].y = r1; }
    }

    // ---- two-half LDS transpose + coalesced full-line nt stores ----
    const int r    = tid & 127;                 // row within half
    const int half = tid >> 7;
#pragma unroll
    for (int h = 0; h < 2; ++h) {
        if (h) __syncthreads();                 // copy of half 0 done
        if (half == h) {
#pragma unroll
            for (int c = 0; c < 8; ++c)
                *(v4f*)&lds[r * 32 + ((c ^ (r & 7)) << 2)] = o[c];
        }
        __syncthreads();
        const long long bp = (long long)blockIdx.x * 256 + h * 128;
        float* const obase = out + (size_t)bp * 32;
#pragma unroll
        for (int j = 0; j < 4; ++j) {
            const int m  = tid + 256 * j;       // 16 B chunk id, 0..1023
            const int pr = m >> 3, c = m & 7;
            if (bp + pr < n) {
                const v4f v = *(const v4f*)&lds[pr * 32 + ((c ^ (pr & 7)) << 2)];
                // 64 lanes x 16 B contiguous = full lines: nt safe
                __builtin_nontemporal_store(v, (v4f*)obase + m);
            }
        }
    }
}

// ---------- Fallback (R1 fused kernel) if ws is too small -------------------
__global__ __launch_bounds__(256) void fused_kernel(
    const float* __restrict__ x, const float* __restrict__ table,
    const float* __restrict__ mask, float* __restrict__ out, int n)
{
    const int p = blockIdx.x * blockDim.x + threadIdx.x;
    if (p >= n) return;
    const float px = x[3 * p + 0], py = x[3 * p + 1], pz = x[3 * p + 2];
    v4f o[8];
#pragma unroll
    for (int lv = 0; lv < kNLevels; ++lv) {
        const float m0 = mask[2 * lv], m1 = mask[2 * lv + 1];
        float r0 = 0.0f, r1 = 0.0f;
        if (m0 != 0.0f || m1 != 0.0f) {
            const int res = kRes[lv];
            const bool dense = ((long long)res * res * res) <= (long long)kT;
            int cx, cy, cz; float wx, wy, wz;
            corner_setup(px, py, pz, res, cx, cy, cz, wx, wy, wz);
            const float ux = 1.0f - wx, uy = 1.0f - wy, uz = 1.0f - wz;
            const float* __restrict__ tbl = table + (size_t)lv * (size_t)(kT * 2);
#pragma unroll
            for (int c = 0; c < 8; ++c) {
                const int dx = c & 1, dy = (c >> 1) & 1, dz = (c >> 2) & 1;
                const int ix = cx + dx, iy = cy + dy, iz = cz + dz;
                uint32_t idx;
                if (dense) idx = (uint32_t)(ix + res * (iy + res * iz));
                else idx = (((uint32_t)ix) ^ ((uint32_t)iy * kP1)
                                           ^ ((uint32_t)iz * kP2)) & (kT - 1u);
                const v2f v = *(const v2f*)(tbl + 2u * idx);
                const float w = (dx ? wx : ux) * (dy ? wy : uy) * (dz ? wz : uz);
                r0 = fmaf(v.x, w, r0);
                r1 = fmaf(v.y, w, r1);
            }
            r0 *= m0; r1 *= m1;
        }
        if (lv & 1) { o[lv >> 1].z = r0; o[lv >> 1].w = r1; }
        else        { o[lv >> 1].x = r0; o[lv >> 1].y = r1; }
    }
    v4f* __restrict__ op = (v4f*)(out + (size_t)p * 32);
#pragma unroll
    for (int i = 0; i < 8; ++i) op[i] = o[i];
}

}  // namespace

extern "C" void kernel_launch(void* const* d_in, const int* in_sizes, int n_in,
                              void* d_out, int out_size, void* d_ws, size_t ws_size,
                              hipStream_t stream) {
    const float* x     = (const float*)d_in[0];
    const float* table = (const float*)d_in[1];
    const float* mask  = (const float*)d_in[2];
    float*       out   = (float*)d_out;

    const int n = in_sizes[0] / 3;  // 1048576 points
    const int block = 256;
    const int gx = (n + block - 1) / block;

    const size_t ws_needed = (size_t)(kNLevels - 5) * (size_t)n * 2 * sizeof(float);
    if (ws_size >= ws_needed) {
        float* ws = (float*)d_ws;
        dim3 grid1(gx, kNLevels - 5);   // hashed levels 5..15 as y-slices
        hashed_level_kernel<<<grid1, block, 0, stream>>>(x, table, mask, ws, n);
        gather_out_kernel<<<gx, block, 0, stream>>>(x, table, ws, mask, out, n);
    } else {
        fused_kernel<<<gx, block, 0, stream>>>(x, table, mask, out, n);
    }
}

// Round 2
// 325.053 us; speedup vs baseline: 1.0796x; 1.0031x over previous
//
#include <hip/hip_runtime.h>
#include <cstdint>
#include <cstddef>

// Instant-NGP hash-grid encode, R7.
//
// History: R1 fused = 247 us (748 MB L2 thrash). R4 two-phase = 210 us.
// R5 hashed-only phase 1 + dense-recompute phase 2 = 350.7 us harness
// (gather_out 130 us). R6 LDS-transpose + full-line nt stores = 326.0 us
// (gather_out 106 us; store line-touches 512->128/wave bought 24 us ->
// calibrates divergent line-touch cost ~2.4 cyc/CU). R6's hashed even/odd
// cx split gained ZERO: per-lane branch -> both paths execute exec-masked.
//
// R7 changes:
//  - hashed_level_kernel: revert even/odd split to the uniform 8-gather
//    loop (divergent branching was a wash); x loaded as one 12 B memcpy.
//  - gather_out: single-phase LDS flush (32 KB, 256 pts x 128 B).
//    R6's two-half flush guarded LDS writes by `half==h`; with o[8]
//    (32 floats) live across phases VGPR_Count=28 is impossible unless
//    the compiler sank/rematerialized work under the branch. Single
//    phase = unconditional writes, one fewer barrier. Occupancy 8->5
//    blocks/CU -- harmless, we are TA-throughput-bound (VALUBusy 11%,
//    HBM 19%).
//  - gather_out: ws nt-loads hoisted BEFORE dense gathers (their L3
//    latency overlaps dense TA work); x as one 12 B memcpy.

namespace {

constexpr int      kNLevels = 16;
constexpr uint32_t kT       = 1u << 19;             // 524288 entries / level
constexpr uint32_t kP1      = 2654435761u;           // tcnn hash primes (y, z)
constexpr uint32_t kP2      = 805459861u;

typedef float v2f __attribute__((ext_vector_type(2)));
typedef float v4f __attribute__((ext_vector_type(4)));

// floor(16 * scale^lv) + 1, scale = exp((ln 2048 - ln 16)/15)
__device__ constexpr int kRes[kNLevels] = {
    17, 23, 31, 43, 59, 81, 112, 154, 213, 295, 407, 562, 777, 1073, 1483, 2049
};
// dense iff res^3 <= T  <=>  res <= 80; levels 0..4 dense, 5..15 hashed.

__device__ inline void corner_setup(float px, float py, float pz, int res,
                                    int& cx, int& cy, int& cz,
                                    float& wx, float& wy, float& wz) {
    const float s = (float)(res - 1);
    const float fx = px * s, fy = py * s, fz = pz * s;
    cx = (int)floorf(fx); cy = (int)floorf(fy); cz = (int)floorf(fz);
    cx = min(max(cx, 0), res - 2);
    cy = min(max(cy, 0), res - 2);
    cz = min(max(cz, 0), res - 2);
    wx = fx - (float)cx; wy = fy - (float)cy; wz = fz - (float)cz;
}

__device__ inline void load_xyz(const float* __restrict__ x, int p,
                                float& px, float& py, float& pz) {
    float v[3];
    __builtin_memcpy(v, x + 3 * (size_t)p, 12);   // dwordx2 + dword
    px = v[0]; py = v[1]; pz = v[2];
}

// ---------- Phase 1: hashed levels 5..15, one blockIdx.y slice per level ----
__global__ __launch_bounds__(256) void hashed_level_kernel(
    const float* __restrict__ x, const float* __restrict__ table,
    const float* __restrict__ mask, float* __restrict__ ws, int n)
{
    const int lv = 5 + blockIdx.y;
    const float m0 = mask[2 * lv], m1 = mask[2 * lv + 1];
    if (m0 == 0.0f && m1 == 0.0f) return;   // masked level: slice exits

    const int p = blockIdx.x * blockDim.x + threadIdx.x;
    if (p >= n) return;
    float px, py, pz;
    load_xyz(x, p, px, py, pz);

    const int res = kRes[lv];
    int cx, cy, cz; float wx, wy, wz;
    corner_setup(px, py, pz, res, cx, cy, cz, wx, wy, wz);
    const float ux = 1.0f - wx, uy = 1.0f - wy, uz = 1.0f - wz;
    const float* __restrict__ tbl = table + (size_t)lv * (size_t)(kT * 2);

    // hash components (CSE'd): idx = (cx+dx) ^ hy[dy] ^ hz[dz], masked
    const uint32_t hy0 = (uint32_t)cy * kP1, hy1 = (uint32_t)(cy + 1) * kP1;
    const uint32_t hz0 = (uint32_t)cz * kP2, hz1 = (uint32_t)(cz + 1) * kP2;
    const uint32_t cxu = (uint32_t)cx;

    float r0 = 0.0f, r1 = 0.0f;
#pragma unroll
    for (int c = 0; c < 8; ++c) {
        const int dx = c & 1, dy = (c >> 1) & 1, dz = (c >> 2) & 1;
        const uint32_t idx =
            ((cxu + (uint32_t)dx) ^ (dy ? hy1 : hy0) ^ (dz ? hz1 : hz0))
            & (kT - 1u);
        const v2f v = *(const v2f*)(tbl + 2u * idx);
        const float w = (dx ? wx : ux) * (dy ? wy : uy) * (dz ? wz : uz);
        r0 = fmaf(v.x, w, r0);
        r1 = fmaf(v.y, w, r1);
    }
    v2f o; o.x = r0; o.y = r1;
    // full-line coalesced (64 lanes x 8 B contiguous): nt is safe here
    __builtin_nontemporal_store(
        o, (v2f*)(ws + ((size_t)(lv - 5) * n + p) * 2));
}

// ---------- Phase 2: dense recompute + hashed readback -> out[N][32] --------
// Single-phase LDS staging (32 KB: 256 pts x 32 floats) then fully
// coalesced full-line nt stores. Swizzle: row r, 16 B chunk c lives at
// float offset r*32 + ((c ^ (r&7)) << 2) -> b128-aligned, conflict-free
// on both per-row writes and the linear copy reads (R6-proven pattern).
__global__ __launch_bounds__(256) void gather_out_kernel(
    const float* __restrict__ x, const float* __restrict__ table,
    const float* __restrict__ ws, const float* __restrict__ mask,
    float* __restrict__ out, int n)
{
    __shared__ float lds[256 * 32];             // 32 KB

    const int tid = threadIdx.x;
    const int p   = blockIdx.x * 256 + tid;
    const int pc  = (p < n) ? p : (n - 1);      // clamp: no early return (barrier)

    float px, py, pz;
    load_xyz(x, pc, px, py, pz);

    v4f o[8];

    // hashed levels 5..15 FIRST: issue ws nt-loads early so their L3
    // latency overlaps the dense gather work below.
#pragma unroll
    for (int lv = 5; lv < kNLevels; ++lv) {
        const float m0 = mask[2 * lv], m1 = mask[2 * lv + 1];
        float r0 = 0.0f, r1 = 0.0f;
        if (m0 != 0.0f || m1 != 0.0f) {
            const v2f v = __builtin_nontemporal_load(
                (const v2f*)(ws + ((size_t)(lv - 5) * n + pc) * 2));
            r0 = v.x * m0;
            r1 = v.y * m1;
        }
        if (lv & 1) { o[lv >> 1].z = r0; o[lv >> 1].w = r1; }
        else        { o[lv >> 1].x = r0; o[lv >> 1].y = r1; }
    }

    // dense levels 0..4: recompute (tables 2.65 MB, chip-wide L2-hot).
#pragma unroll
    for (int lv = 0; lv < 5; ++lv) {
        const float m0 = mask[2 * lv], m1 = mask[2 * lv + 1];
        float r0 = 0.0f, r1 = 0.0f;
        if (m0 != 0.0f || m1 != 0.0f) {
            const int res = kRes[lv];
            int cx, cy, cz; float wx, wy, wz;
            corner_setup(px, py, pz, res, cx, cy, cz, wx, wy, wz);
            const float ux = 1.0f - wx, uy = 1.0f - wy, uz = 1.0f - wz;
            const float* __restrict__ tbl = table + (size_t)lv * (size_t)(kT * 2);
#pragma unroll
            for (int c = 0; c < 4; ++c) {
                const int dy = c & 1, dz = (c >> 1) & 1;
                const uint32_t idx0 =
                    (uint32_t)(cx + res * ((cy + dy) + res * (cz + dz)));
                // entries idx0 and idx0+1 are the two x-corners: one 16 B load
                v4f ab;
                __builtin_memcpy(&ab, tbl + 2u * idx0, sizeof(v4f));
                const float wyz = (dy ? wy : uy) * (dz ? wz : uz);
                const float w0 = ux * wyz, w1 = wx * wyz;
                r0 = fmaf(ab.x, w0, fmaf(ab.z, w1, r0));
                r1 = fmaf(ab.y, w0, fmaf(ab.w, w1, r1));
            }
            r0 *= m0; r1 *= m1;
        }
        if (lv & 1) { o[lv >> 1].z = r0; o[lv >> 1].w = r1; }
        else        { o[lv >> 1].x = r0; o[lv >> 1].y = r1; }
    }

    // ---- single-phase LDS transpose + coalesced full-line nt stores ----
#pragma unroll
    for (int c = 0; c < 8; ++c)
        *(v4f*)&lds[tid * 32 + ((c ^ (tid & 7)) << 2)] = o[c];
    __syncthreads();

    const long long bp = (long long)blockIdx.x * 256;
    float* const obase = out + (size_t)bp * 32;
#pragma unroll
    for (int j = 0; j < 8; ++j) {
        const int m  = tid + 256 * j;           // 16 B chunk id, 0..2047
        const int pr = m >> 3, c = m & 7;
        if (bp + pr < n) {
            const v4f v = *(const v4f*)&lds[pr * 32 + ((c ^ (pr & 7)) << 2)];
            // 64 lanes x 16 B contiguous = full lines: nt safe
            __builtin_nontemporal_store(v, (v4f*)obase + m);
        }
    }
}

// ---------- Fallback (R1 fused kernel) if ws is too small -------------------
__global__ __launch_bounds__(256) void fused_kernel(
    const float* __restrict__ x, const float* __restrict__ table,
    const float* __restrict__ mask, float* __restrict__ out, int n)
{
    const int p = blockIdx.x * blockDim.x + threadIdx.x;
    if (p >= n) return;
    const float px = x[3 * p + 0], py = x[3 * p + 1], pz = x[3 * p + 2];
    v4f o[8];
#pragma unroll
    for (int lv = 0; lv < kNLevels; ++lv) {
        const float m0 = mask[2 * lv], m1 = mask[2 * lv + 1];
        float r0 = 0.0f, r1 = 0.0f;
        if (m0 != 0.0f || m1 != 0.0f) {
            const int res = kRes[lv];
            const bool dense = ((long long)res * res * res) <= (long long)kT;
            int cx, cy, cz; float wx, wy, wz;
            corner_setup(px, py, pz, res, cx, cy, cz, wx, wy, wz);
            const float ux = 1.0f - wx, uy = 1.0f - wy, uz = 1.0f - wz;
            const float* __restrict__ tbl = table + (size_t)lv * (size_t)(kT * 2);
#pragma unroll
            for (int c = 0; c < 8; ++c) {
                const int dx = c & 1, dy = (c >> 1) & 1, dz = (c >> 2) & 1;
                const int ix = cx + dx, iy = cy + dy, iz = cz + dz;
                uint32_t idx;
                if (dense) idx = (uint32_t)(ix + res * (iy + res * iz));
                else idx = (((uint32_t)ix) ^ ((uint32_t)iy * kP1)
                                           ^ ((uint32_t)iz * kP2)) & (kT - 1u);
                const v2f v = *(const v2f*)(tbl + 2u * idx);
                const float w = (dx ? wx : ux) * (dy ? wy : uy) * (dz ? wz : uz);
                r0 = fmaf(v.x, w, r0);
                r1 = fmaf(v.y, w, r1);
            }
            r0 *= m0; r1 *= m1;
        }
        if (lv & 1) { o[lv >> 1].z = r0; o[lv >> 1].w = r1; }
        else        { o[lv >> 1].x = r0; o[lv >> 1].y = r1; }
    }
    v4f* __restrict__ op = (v4f*)(out + (size_t)p * 32);
#pragma unroll
    for (int i = 0; i < 8; ++i) op[i] = o[i];
}

}  // namespace

extern "C" void kernel_launch(void* const* d_in, const int* in_sizes, int n_in,
                              void* d_out, int out_size, void* d_ws, size_t ws_size,
                              hipStream_t stream) {
    const float* x     = (const float*)d_in[0];
    const float* table = (const float*)d_in[1];
    const float* mask  = (const float*)d_in[2];
    float*       out   = (float*)d_out;

    const int n = in_sizes[0] / 3;  // 1048576 points
    const int block = 256;
    const int gx = (n + block - 1) / block;

    const size_t ws_needed = (size_t)(kNLevels - 5) * (size_t)n * 2 * sizeof(float);
    if (ws_size >= ws_needed) {
        float* ws = (float*)d_ws;
        dim3 grid1(gx, kNLevels - 5);   // hashed levels 5..15 as y-slices
        hashed_level_kernel<<<grid1, block, 0, stream>>>(x, table, mask, ws, n);
        gather_out_kernel<<<gx, block, 0, stream>>>(x, table, ws, mask, out, n);
    } else {
        fused_kernel<<<gx, block, 0, stream>>>(x, table, mask, out, n);
    }
}